// Round 1
// baseline (324.517 us; speedup 1.0000x reference)
//
#include <hip/hip_runtime.h>
#include <stdint.h>

// Problem constants
#define ENC2 1024   // 2*ENC_HID = K of main GEMM
#define DECH 1024
#define ADIM 1024   // N (attn dim)
#define BB   32
#define SS   1024
#define MTOT (BB*SS)   // 32768

typedef _Float16 half_t;
typedef __attribute__((ext_vector_type(8))) _Float16 half8;
typedef __attribute__((ext_vector_type(4))) float    f32x4;

// ---------------------------------------------------------------------------
// K0: Wt[n][k] = (fp16) W_enc[k][n]  (W_enc = W rows 1024..2047), tiled transpose
// ---------------------------------------------------------------------------
__global__ __launch_bounds__(256) void k_wt(const float* __restrict__ W,
                                            half_t* __restrict__ Wt) {
    __shared__ float tile[64][65];
    const int bx = blockIdx.x & 15;   // k-tile
    const int by = blockIdx.x >> 4;   // n-tile
    const int k0 = bx * 64, n0 = by * 64;
    const int t = threadIdx.x;
    #pragma unroll
    for (int i = 0; i < 16; i++) {
        int idx = t + i * 256;
        int r = idx >> 6, c = idx & 63;
        tile[r][c] = W[(size_t)(DECH + k0 + r) * ADIM + n0 + c];
    }
    __syncthreads();
    #pragma unroll
    for (int i = 0; i < 16; i++) {
        int idx = t + i * 256;
        int rn = idx >> 6, ck = idx & 63;
        Wt[(size_t)(n0 + rn) * ENC2 + k0 + ck] = (half_t)tile[ck][rn];
    }
}

// ---------------------------------------------------------------------------
// K1: dec_proj[b][a] = dh[b] . W_dec[:,a] + bias[a]   (fp32, exact)
// grid 256 = 32 b * 8 col-chunks of 128; 256 thr = 128 cols * 2 k-halves
// ---------------------------------------------------------------------------
__global__ __launch_bounds__(256) void k_decp(const float* __restrict__ dh,
                                              const float* __restrict__ W,
                                              const float* __restrict__ bias,
                                              float* __restrict__ decp) {
    __shared__ float part[2][128];
    const int b  = blockIdx.x >> 3;
    const int a0 = (blockIdx.x & 7) * 128;
    const int t = threadIdx.x;
    const int col = t & 127, kh = t >> 7;
    const float* dhrow = dh + (size_t)b * DECH + kh * 512;
    const float* Wp    = W + (size_t)(kh * 512) * ADIM + a0 + col;
    float s = 0.f;
    for (int kk = 0; kk < 512; kk++)
        s += dhrow[kk] * Wp[(size_t)kk * ADIM];
    part[kh][col] = s;
    __syncthreads();
    if (t < 128)
        decp[(size_t)b * ADIM + a0 + t] = part[0][t] + part[1][t] + bias[a0 + t];
}

// ---------------------------------------------------------------------------
// K2: fused GEMM(fp16 MFMA) + tanh + dot(v) -> scores (fp32 atomics)
// Tile 128x256, BK=32, 512 thr (8 waves of 64x64 = 4x4 of 16x16x32).
// grid 256 = 4 n-tiles * 64 m-groups; block loops 4 m-chunks of 128 rows,
// so A (encoder) streams once and W stays L2-resident. bid = nb*64+mg puts
// the 4 blocks sharing an A-stream on one XCD (bid%8 round-robin).
// ---------------------------------------------------------------------------
#define BM 128
#define BN 256
#define BK 32
#define LDA 40   // 32 + 8 pad (halfs) -> conflict-free ds_read_b128
#define LDB 40

__global__ __launch_bounds__(512) void k_main(const float* __restrict__ enc,
                                              const half_t* __restrict__ Wt,
                                              const float* __restrict__ decp,
                                              const float* __restrict__ v,
                                              float* __restrict__ scores) {
    __shared__ half_t lsA[2][BM][LDA];   // 20480 B
    __shared__ half_t lsB[2][BN][LDB];   // 40960 B

    const int bid = blockIdx.x;
    const int nb = bid >> 6;         // 0..3   n-tile
    const int mg = bid & 63;         // 0..63  m-group (512 rows)
    const int n0 = nb * BN;
    const int t = threadIdx.x;
    const int w = t >> 6;            // wave 0..7
    const int L = t & 63;
    const int wm = w & 1, wn = w >> 1;       // 2 x 4 wave grid
    const int lane15 = L & 15, quad = L >> 4;
    const int bIdx = mg >> 1;        // batch index (512 rows per group, 1024/b)

    // staging assignments
    const int arow = t >> 2;             // 0..127
    const int akc  = (t & 3) * 8;        // k offset within BK (8 floats/thread)
    const int brow = t >> 1;             // 0..255
    const int bkc  = (t & 1) * 16;       // 16 halfs/thread

    const half_t* WtB = Wt + (size_t)(n0 + brow) * ENC2 + bkc;

    // epilogue per-lane column constants (same for all m-chunks)
    float vv[4], dp[4];
    #pragma unroll
    for (int sn = 0; sn < 4; sn++) {
        int ng = n0 + wn * 64 + sn * 16 + lane15;
        vv[sn] = v[ng];
        dp[sn] = decp[(size_t)bIdx * ADIM + ng];
    }

    for (int mc = 0; mc < 4; mc++) {
        const int m0 = mg * 512 + mc * 128;
        const float* Arow = enc + (size_t)(m0 + arow) * ENC2 + akc;

        f32x4 acc[4][4];
        #pragma unroll
        for (int i = 0; i < 4; i++) {
            #pragma unroll
            for (int j = 0; j < 4; j++) acc[i][j] = (f32x4)0.f;
        }

        float4 ra0, ra1; uint4 rb0, rb1;
        auto loadA = [&](int ks) {
            const float* p = Arow + ks * BK;
            ra0 = *(const float4*)p;
            ra1 = *(const float4*)(p + 4);
        };
        auto loadB = [&](int ks) {
            const half_t* p = WtB + ks * BK;
            rb0 = *(const uint4*)p;
            rb1 = *(const uint4*)(p + 8);
        };
        auto writeL = [&](int pb) {
            half8 ha;
            ha[0] = (half_t)ra0.x; ha[1] = (half_t)ra0.y;
            ha[2] = (half_t)ra0.z; ha[3] = (half_t)ra0.w;
            ha[4] = (half_t)ra1.x; ha[5] = (half_t)ra1.y;
            ha[6] = (half_t)ra1.z; ha[7] = (half_t)ra1.w;
            *(half8*)&lsA[pb][arow][akc] = ha;
            *(uint4*)&lsB[pb][brow][bkc]     = rb0;
            *(uint4*)&lsB[pb][brow][bkc + 8] = rb1;
        };

        // software pipeline: write k, prefetch k+1 in regs
        loadA(0); loadB(0);
        writeL(0);
        loadA(1); loadB(1);
        __syncthreads();

        for (int ks = 0; ks < ENC2 / BK; ks++) {
            const int cur = ks & 1;
            if (ks < ENC2 / BK - 1) {
                writeL(cur ^ 1);
                if (ks < ENC2 / BK - 2) { loadA(ks + 2); loadB(ks + 2); }
            }
            half8 af[4], bf[4];
            #pragma unroll
            for (int sm = 0; sm < 4; sm++)
                af[sm] = *(const half8*)&lsA[cur][wm * 64 + sm * 16 + lane15][quad * 8];
            #pragma unroll
            for (int sn = 0; sn < 4; sn++)
                bf[sn] = *(const half8*)&lsB[cur][wn * 64 + sn * 16 + lane15][quad * 8];
            #pragma unroll
            for (int sm = 0; sm < 4; sm++) {
                #pragma unroll
                for (int sn = 0; sn < 4; sn++)
                    acc[sm][sn] = __builtin_amdgcn_mfma_f32_16x16x32_f16(
                        af[sm], bf[sn], acc[sm][sn], 0, 0, 0);
            }
            __syncthreads();
        }

        // epilogue: energy = tanh(acc + dec_proj), partial score = sum_n energy*v
        // C/D layout: row(m) = quad*4 + reg, col(n) = lane15  [m89-verified]
        #pragma unroll
        for (int sm = 0; sm < 4; sm++) {
            #pragma unroll
            for (int rr = 0; rr < 4; rr++) {
                float s = 0.f;
                #pragma unroll
                for (int sn = 0; sn < 4; sn++) {
                    float x = acc[sm][sn][rr] + dp[sn];
                    // tanh(x) = 1 - 2/(exp(2x)+1); exp(2x) = 2^(x*2/ln2)
                    float e  = __builtin_amdgcn_exp2f(x * 2.8853900817779268f);
                    float th = 1.f - 2.f * __builtin_amdgcn_rcpf(e + 1.f);
                    s += th * vv[sn];
                }
                // reduce across the 16 col-lanes (low 4 lane bits)
                s += __shfl_xor(s, 1, 64);
                s += __shfl_xor(s, 2, 64);
                s += __shfl_xor(s, 4, 64);
                s += __shfl_xor(s, 8, 64);
                if (lane15 == 0) {
                    int mlocal = wm * 64 + sm * 16 + quad * 4 + rr;
                    atomicAdd(&scores[(size_t)m0 + mlocal], s);
                }
            }
        }
    }
}

// ---------------------------------------------------------------------------
// K3: row softmax over S=1024 per batch row
// ---------------------------------------------------------------------------
__global__ __launch_bounds__(256) void k_softmax(const float* __restrict__ scores,
                                                 float* __restrict__ out) {
    __shared__ float red[8];
    const int b = blockIdx.x, t = threadIdx.x;
    const float* row = scores + (size_t)b * SS;
    float x[4];
    #pragma unroll
    for (int i = 0; i < 4; i++) x[i] = row[t + i * 256];
    float mx = fmaxf(fmaxf(x[0], x[1]), fmaxf(x[2], x[3]));
    #pragma unroll
    for (int d = 1; d < 64; d <<= 1) mx = fmaxf(mx, __shfl_xor(mx, d, 64));
    if ((t & 63) == 0) red[t >> 6] = mx;
    __syncthreads();
    mx = fmaxf(fmaxf(red[0], red[1]), fmaxf(red[2], red[3]));
    float e[4], s = 0.f;
    #pragma unroll
    for (int i = 0; i < 4; i++) {
        e[i] = __builtin_amdgcn_exp2f((x[i] - mx) * 1.4426950408889634f);
        s += e[i];
    }
    #pragma unroll
    for (int d = 1; d < 64; d <<= 1) s += __shfl_xor(s, d, 64);
    if ((t & 63) == 0) red[4 + (t >> 6)] = s;
    __syncthreads();
    s = red[4] + red[5] + red[6] + red[7];
    float inv = 1.f / s;
    #pragma unroll
    for (int i = 0; i < 4; i++) out[(size_t)b * SS + t + i * 256] = e[i] * inv;
}

// ---------------------------------------------------------------------------
extern "C" void kernel_launch(void* const* d_in, const int* in_sizes, int n_in,
                              void* d_out, int out_size, void* d_ws, size_t ws_size,
                              hipStream_t stream) {
    const float* dh   = (const float*)d_in[0];  // (32,1024)
    const float* enc  = (const float*)d_in[1];  // (32,1024,1024)
    const float* W    = (const float*)d_in[2];  // (2048,1024)
    const float* bias = (const float*)d_in[3];  // (1024,)
    const float* v    = (const float*)d_in[4];  // (1024,)
    float* out = (float*)d_out;

    char* ws = (char*)d_ws;
    half_t* Wt    = (half_t*)ws;                                    // 2 MB
    float*  decp  = (float*)(ws + 2u * 1024 * 1024);                // 128 KB
    float*  scores = (float*)(ws + 2u * 1024 * 1024 + 128 * 1024);  // 128 KB

    k_wt  <<<256, 256, 0, stream>>>(W, Wt);
    k_decp<<<256, 256, 0, stream>>>(dh, W, bias, decp);
    hipMemsetAsync(scores, 0, (size_t)BB * SS * sizeof(float), stream);
    k_main<<<256, 512, 0, stream>>>(enc, Wt, decp, v, scores);
    k_softmax<<<32, 256, 0, stream>>>(scores, out);
}